// Round 18
// baseline (271.237 us; speedup 1.0000x reference)
//
#include <hip/hip_runtime.h>

typedef unsigned short u16;
typedef __attribute__((ext_vector_type(4))) unsigned short u16x4;
typedef __attribute__((ext_vector_type(2))) unsigned int u32x2;
typedef __attribute__((ext_vector_type(4))) unsigned int u32x4;
typedef __attribute__((ext_vector_type(4))) short s16x4;
typedef __attribute__((ext_vector_type(8))) short bf16x8;
typedef __attribute__((ext_vector_type(4))) float f32x4;

#define MFMA16(a, b, c) __builtin_amdgcn_mfma_f32_16x16x32_bf16((a), (b), (c), 0, 0, 0)
// K=16 MFMA: A/B frag k-layout = lg*4+{0..3} == C-layout acc row grouping ->
// C-layout accumulators feed it with ZERO cross-lane movement. (r11 proven)
#define MFMAK16(a, b, c) \
  __builtin_amdgcn_mfma_f32_16x16x16bf16_1k( \
      __builtin_bit_cast(s16x4, (a)), __builtin_bit_cast(s16x4, (b)), (c), 0, 0, 0)

__device__ __forceinline__ u16 f2bf(float f) {
  unsigned u = __builtin_bit_cast(unsigned, f);
  u += 0x7FFFu + ((u >> 16) & 1u);  // round-to-nearest-even
  return (u16)(u >> 16);
}
__device__ __forceinline__ float bf2f(u16 v) {
  return __builtin_bit_cast(float, (unsigned)v << 16);
}
__device__ __forceinline__ unsigned cvtpk(float lo, float hi) {
  unsigned r;
  asm("v_cvt_pk_bf16_f32 %0, %1, %2" : "=v"(r) : "v"(lo), "v"(hi));
  return r;
}

// XOR-swizzled [64][256] bf16: 16-B block (r*32 + c>>3)^(r&7)
__device__ __forceinline__ int idx256(int r, int c) {
  int blk = ((r << 5) + (c >> 3)) ^ (r & 7);
  return (blk << 3) + (c & 7);
}

// ---------------- stats pass 1 ----------------
__global__ __launch_bounds__(256) void k_stats1(const float* __restrict__ x,
                                                float* __restrict__ part) {
  int bid = blockIdx.x;
  int s = bid & 15, bg = bid >> 4;
  const float4* p = (const float4*)(x + ((size_t)bg << 19) + ((size_t)s << 15));
  float sm = 0.f, ss = 0.f;
  for (int i = threadIdx.x; i < 8192; i += 256) {
    float4 v = p[i];
    sm += v.x + v.y + v.z + v.w;
    ss += v.x * v.x + v.y * v.y + v.z * v.z + v.w * v.w;
  }
  #pragma unroll
  for (int off = 1; off < 64; off <<= 1) {
    sm += __shfl_xor(sm, off);
    ss += __shfl_xor(ss, off);
  }
  __shared__ float ls[4], lss[4];
  int wv = threadIdx.x >> 6;
  if ((threadIdx.x & 63) == 0) { ls[wv] = sm; lss[wv] = ss; }
  __syncthreads();
  if (threadIdx.x == 0) {
    part[bid * 2] = ls[0] + ls[1] + ls[2] + ls[3];
    part[bid * 2 + 1] = lss[0] + lss[1] + lss[2] + lss[3];
  }
}

// ---------------- stats pass 2 ----------------
__global__ __launch_bounds__(64) void k_stats2(const float* __restrict__ part,
                                               float* __restrict__ stats) {
  int t = threadIdx.x;
  float S = 0.f, SS = 0.f;
  #pragma unroll
  for (int s = 0; s < 16; ++s) {
    S += part[(t * 16 + s) * 2];
    SS += part[(t * 16 + s) * 2 + 1];
  }
  const float inv = 1.f / 524288.f;
  float mean = S * inv;
  float var = SS * inv - mean * mean;
  stats[t * 2] = mean;
  stats[t * 2 + 1] = rsqrtf(var + 1e-5f);
}

// ------- weights bf16 + lane-permuted bias table [h][tile16][lane64][rj4] * log2e -------
__global__ __launch_bounds__(256) void k_prep(const float* __restrict__ qkv_w,
                                              const float* __restrict__ proj_w,
                                              const float* __restrict__ rpb,
                                              u16* __restrict__ qkvw,
                                              u16* __restrict__ projw,
                                              float* __restrict__ biast2) {
  int i = blockIdx.x * 256 + threadIdx.x;
  if (i < 196608) qkvw[i] = f2bf(qkv_w[i]);
  if (i < 65536) projw[i] = f2bf(proj_w[i]);
  if (i < 32768) {
    int h = i >> 12;
    int rem = i & 4095;
    int tile = rem >> 8, lane = (rem >> 2) & 63, rj = rem & 3;
    int tms = tile >> 2, tq = tile & 3;
    int lg = lane >> 4, lr = lane & 15;
    int key = (tms << 4) + (lg << 2) + rj;
    int q = (tq << 4) + lr;
    int qd = q >> 4, qh = (q >> 2) & 3, qw = q & 3;
    int kd = key >> 4, kh = (key >> 2) & 3, kw = key & 3;
    int r = (qd - kd + 3) * 49 + (qh - kh + 3) * 7 + (qw - kw + 3);
    biast2[i] = rpb[r * 8 + h] * 1.4426950408889634f;
  }
}

// ---------------- norm + window partition + transpose -> stage ----------------
__global__ __launch_bounds__(256) void k_win(const float* __restrict__ x,
                                             const float* __restrict__ norm_w,
                                             const float* __restrict__ norm_b,
                                             const float* __restrict__ stats,
                                             u16* __restrict__ stage) {
  __shared__ __attribute__((aligned(16))) u16 T[16384];
  int bid = blockIdx.x;
  int b = bid >> 10, sd = (bid >> 6) & 15, sh = bid & 63;
  int wq = threadIdx.x & 15, c_lo = threadIdx.x >> 4;
  int w0 = wq << 2;

  for (int c_hi = 0; c_hi < 16; ++c_hi) {
    int c = (c_hi << 4) + c_lo;
    int g = c >> 3;
    float mean = stats[((b << 5) + g) * 2];
    float rstd = stats[((b << 5) + g) * 2 + 1];
    float gw = norm_w[c] * rstd;
    float gb = norm_b[c] - mean * gw;
    float4 v = *(const float4*)(x + (((size_t)(b * 256 + c)) << 16) + (sd << 12) +
                                (sh << 6) + w0);
    int cp = (c + w0) & 255;
    T[((w0 + 0) << 8) + cp] = f2bf(fmaf(v.x, gw, gb));
    T[((w0 + 1) << 8) + cp] = f2bf(fmaf(v.y, gw, gb));
    T[((w0 + 2) << 8) + cp] = f2bf(fmaf(v.z, gw, gb));
    T[((w0 + 3) << 8) + cp] = f2bf(fmaf(v.w, gw, gb));
  }
  __syncthreads();

  int wv = threadIdx.x >> 6, l = threadIdx.x & 63;
  int ud = (sd + 14) & 15, wd = ud >> 2, td = ud & 3;
  int uh = (sh + 62) & 63, wh = uh >> 2, th = uh & 3;
  int winbase = (b << 10) + (wd << 8) + (wh << 4);
  int tokbase = (td << 4) + (th << 2);
  for (int it = 0; it < 16; ++it) {
    int sw = (it << 2) + wv;
    int uw = (sw + 62) & 63, ww = uw >> 2, tw = uw & 3;
    int row = ((winbase + ww) << 6) + tokbase + tw;
    u16x4 val = *(const u16x4*)&T[(sw << 8) + (((l << 2) + (sw & 252)) & 255)];
    *(u16x4*)&stage[((size_t)row << 8) + (l << 2)] = val;
  }
}

// ------- attention: 256 thr / 4 waves, 4 heads per block (2 blocks per window),
//         two-pass QKV (register diet), direct O stores, both halves unrolled -------
__global__ __launch_bounds__(256) void k_attn(
    const float* __restrict__ qkv_b, const u16* __restrict__ qkvw,
    const float* __restrict__ biast2, u16* __restrict__ stage) {
  __shared__ __attribute__((aligned(16))) u16 sXN[16384];  // 32 KB [64][256] swz

  const int tid = threadIdx.x;
  const int bid = blockIdx.x;
  const int win = bid >> 1;
  const int sub = bid & 1;  // head group: h = sub*4 + wv
  const int lane = tid & 63;
  const int wv = tid >> 6;
  const int lr = lane & 15;
  const int lg = lane >> 4;
  u16* wbase = stage + ((size_t)win << 14);

  // phase 1: coalesced pre-swizzled load of the window into sXN (4 waves x 8 iters)
  #pragma unroll
  for (int it = 0; it < 8; ++it) {
    int r = (it << 3) + (wv << 1) + (lane >> 5);
    int p = lane & 31;
    u32x4 v = *(const u32x4*)(wbase + (r << 8) + ((p ^ (r & 7)) << 3));
    *(u32x4*)&sXN[(r << 8) + (p << 3)] = v;
  }
  __syncthreads();  // the only barrier

  // 1/sqrt(32) * log2(e): softmax runs in exp2 domain
  const float SCALE = 0.17677669529663687f * 1.4426950408889634f;
  const int h = (sub << 2) + wv;
  const int woQ = (h << 5);
  const int woK = 256 + (h << 5);
  const int woV = 512 + (h << 5);

  u32x2 qB[2][4], kA[2][4], vB[4][2];

  // ---- Pass A: Q,K operand-swapped (acc [d][tok]); peak live acc = 64 f32 ----
  {
    f32x4 aQ[2][4], aK[2][4];
    float4 q0 = *(const float4*)&qkv_b[woQ + (lg << 2)];
    float4 q1 = *(const float4*)&qkv_b[woQ + 16 + (lg << 2)];
    float4 k0 = *(const float4*)&qkv_b[woK + (lg << 2)];
    float4 k1 = *(const float4*)&qkv_b[woK + 16 + (lg << 2)];
    #pragma unroll
    for (int xt = 0; xt < 4; ++xt) {
      aQ[0][xt][0] = q0.x; aQ[0][xt][1] = q0.y; aQ[0][xt][2] = q0.z; aQ[0][xt][3] = q0.w;
      aQ[1][xt][0] = q1.x; aQ[1][xt][1] = q1.y; aQ[1][xt][2] = q1.z; aQ[1][xt][3] = q1.w;
      aK[0][xt][0] = k0.x; aK[0][xt][1] = k0.y; aK[0][xt][2] = k0.z; aK[0][xt][3] = k0.w;
      aK[1][xt][0] = k1.x; aK[1][xt][1] = k1.y; aK[1][xt][2] = k1.z; aK[1][xt][3] = k1.w;
    }
    #pragma unroll 2
    for (int kk = 0; kk < 8; ++kk) {
      const int c0 = kk << 5;
      bf16x8 xb[4], wq_[2], wk_[2];
      #pragma unroll
      for (int t = 0; t < 4; ++t)
        xb[t] = *(const bf16x8*)&sXN[idx256((t << 4) + lr, c0 + (lg << 3))];
      #pragma unroll
      for (int t = 0; t < 2; ++t) {
        wq_[t] = *(const bf16x8*)&qkvw[((woQ + (t << 4) + lr) << 8) + c0 + (lg << 3)];
        wk_[t] = *(const bf16x8*)&qkvw[((woK + (t << 4) + lr) << 8) + c0 + (lg << 3)];
      }
      #pragma unroll
      for (int wt = 0; wt < 2; ++wt)
        #pragma unroll
        for (int xt = 0; xt < 4; ++xt) {
          aQ[wt][xt] = MFMA16(wq_[wt], xb[xt], aQ[wt][xt]);
          aK[wt][xt] = MFMA16(wk_[wt], xb[xt], aK[wt][xt]);
        }
    }
    #pragma unroll
    for (int wt = 0; wt < 2; ++wt)
      #pragma unroll
      for (int xt = 0; xt < 4; ++xt) {
        u32x2 tq = {cvtpk(aQ[wt][xt][0] * SCALE, aQ[wt][xt][1] * SCALE),
                    cvtpk(aQ[wt][xt][2] * SCALE, aQ[wt][xt][3] * SCALE)};
        qB[wt][xt] = tq;
        u32x2 tk = {cvtpk(aK[wt][xt][0], aK[wt][xt][1]),
                    cvtpk(aK[wt][xt][2], aK[wt][xt][3])};
        kA[wt][xt] = tk;
      }
  }

  // ---- Pass B: V normal (acc [tok][d]); peak live acc = 32 f32 ----
  {
    f32x4 aV[4][2];
    float v0 = qkv_b[woV + lr];
    float v1 = qkv_b[woV + 16 + lr];
    #pragma unroll
    for (int tm = 0; tm < 4; ++tm) {
      f32x4 z0 = {v0, v0, v0, v0};
      f32x4 z1 = {v1, v1, v1, v1};
      aV[tm][0] = z0;
      aV[tm][1] = z1;
    }
    #pragma unroll 2
    for (int kk = 0; kk < 8; ++kk) {
      const int c0 = kk << 5;
      bf16x8 xb[4], wv_[2];
      #pragma unroll
      for (int t = 0; t < 4; ++t)
        xb[t] = *(const bf16x8*)&sXN[idx256((t << 4) + lr, c0 + (lg << 3))];
      #pragma unroll
      for (int t = 0; t < 2; ++t)
        wv_[t] = *(const bf16x8*)&qkvw[((woV + (t << 4) + lr) << 8) + c0 + (lg << 3)];
      #pragma unroll
      for (int tm = 0; tm < 4; ++tm)
        #pragma unroll
        for (int td = 0; td < 2; ++td)
          aV[tm][td] = MFMA16(xb[tm], wv_[td], aV[tm][td]);
    }
    #pragma unroll
    for (int tm = 0; tm < 4; ++tm)
      #pragma unroll
      for (int td = 0; td < 2; ++td) {
        u32x2 tv = {cvtpk(aV[tm][td][0], aV[tm][td][1]),
                    cvtpk(aV[tm][td][2], aV[tm][td][3])};
        vB[tm][td] = tv;
      }
  }

  // ---- S^T + softmax + PV, both halves unrolled (independent chains) ----
  #pragma unroll
  for (int half = 0; half < 2; ++half) {
    f32x4 s2[4][2];
    #pragma unroll
    for (int tms = 0; tms < 4; ++tms)
      #pragma unroll
      for (int tn2 = 0; tn2 < 2; ++tn2)
        s2[tms][tn2] = *(const f32x4*)&biast2[
            (((h << 4) + (tms << 2) + (half << 1) + tn2) << 8) + (lane << 2)];
    __builtin_amdgcn_s_setprio(1);
    #pragma unroll
    for (int tms = 0; tms < 4; ++tms)
      #pragma unroll
      for (int tn2 = 0; tn2 < 2; ++tn2) {
        s2[tms][tn2] = MFMAK16(kA[0][tms], qB[0][(half << 1) + tn2], s2[tms][tn2]);
        s2[tms][tn2] = MFMAK16(kA[1][tms], qB[1][(half << 1) + tn2], s2[tms][tn2]);
      }
    __builtin_amdgcn_s_setprio(0);

    // softmax over keys, exp2 domain, no max-subtract (|S| bounded; r15 proven)
    #pragma unroll
    for (int tn2 = 0; tn2 < 2; ++tn2) {
      float sum = 0.f;
      #pragma unroll
      for (int tms = 0; tms < 4; ++tms)
        #pragma unroll
        for (int rj = 0; rj < 4; ++rj) {
          float e = exp2f(s2[tms][tn2][rj]);
          s2[tms][tn2][rj] = e;
          sum += e;
        }
      sum += __shfl_xor(sum, 16);
      sum += __shfl_xor(sum, 32);
      float inv = 1.f / sum;
      #pragma unroll
      for (int tms = 0; tms < 4; ++tms)
        #pragma unroll
        for (int rj = 0; rj < 4; ++rj) s2[tms][tn2][rj] *= inv;
    }

    // P as K16 A-frag directly from s2 (lane lr = q, k = key rows): cvt_pk only
    u32x2 pf[4][2];
    #pragma unroll
    for (int tms = 0; tms < 4; ++tms)
      #pragma unroll
      for (int tn2 = 0; tn2 < 2; ++tn2) {
        u32x2 t = {cvtpk(s2[tms][tn2][0], s2[tms][tn2][1]),
                   cvtpk(s2[tms][tn2][2], s2[tms][tn2][3])};
        pf[tms][tn2] = t;
      }

    // O[q][d] = P·V : o[tn2(q-tile)][dt(d-tile)], accumulate over 4 key-tiles
    f32x4 o[2][2];
    {
      f32x4 z = {0.f, 0.f, 0.f, 0.f};
      #pragma unroll
      for (int tn2 = 0; tn2 < 2; ++tn2)
        #pragma unroll
        for (int dt = 0; dt < 2; ++dt) o[tn2][dt] = z;
    }
    __builtin_amdgcn_s_setprio(1);
    #pragma unroll
    for (int tms = 0; tms < 4; ++tms)
      #pragma unroll
      for (int tn2 = 0; tn2 < 2; ++tn2)
        #pragma unroll
        for (int dt = 0; dt < 2; ++dt)
          o[tn2][dt] = MFMAK16(pf[tms][tn2], vB[tms][dt], o[tn2][dt]);
    __builtin_amdgcn_s_setprio(0);

    // direct global O stores (in-place over stage; this block's sXN copy is done,
    // and the sibling block writes only its own 4 heads' channel slices).
    // token q = (half<<5)+(tn2<<4)+(lg<<2)+rj, ch = (h<<5)+(dt<<4)+lr
    #pragma unroll
    for (int tn2 = 0; tn2 < 2; ++tn2)
      #pragma unroll
      for (int dt = 0; dt < 2; ++dt)
        #pragma unroll
        for (int rj = 0; rj < 4; ++rj) {
          int q = (half << 5) + (tn2 << 4) + (lg << 2) + rj;
          wbase[(q << 8) + (h << 5) + (dt << 4) + lr] = f2bf(o[tn2][dt][rj]);
        }
  }
}

// ---------------- proj GEMM + window reverse + residual (fused) ----------------
__global__ __launch_bounds__(256, 4) void k_pout(
    const float* __restrict__ x, const u16* __restrict__ stage,
    const float* __restrict__ proj_b, const u16* __restrict__ projw,
    float* __restrict__ out) {
  __shared__ __attribute__((aligned(16))) u16 T[16384];  // 32 KB, reused per phase
  int bid = blockIdx.x;
  int b = bid >> 10, sd = (bid >> 6) & 15, sh = bid & 63;
  int wv = threadIdx.x >> 6, l = threadIdx.x & 63;
  int lr = l & 15, lg = l >> 4;
  int ud = (sd + 14) & 15, wd = ud >> 2, td = ud & 3;
  int uh = (sh + 62) & 63, wh = uh >> 2, th = uh & 3;
  int winbase = (b << 10) + (wd << 8) + (wh << 4);
  int tokbase = (td << 4) + (th << 2);

  // phase 1: gather O rows (coalesced 512-B) -> T in idx256-swizzled layout
  #pragma unroll
  for (int it = 0; it < 16; ++it) {
    int sw = (it << 2) + wv;
    int uw = (sw + 62) & 63, ww = uw >> 2, tw = uw & 3;
    int row = ((winbase + ww) << 6) + tokbase + tw;
    u16x4 val = *(const u16x4*)&stage[((size_t)row << 8) + (l << 2)];
    int blk = ((sw << 5) + (l >> 1)) ^ (sw & 7);
    *(u16x4*)&T[(blk << 3) + ((l & 1) << 2)] = val;
  }
  __syncthreads();

  // phase 2: proj GEMM 64x256, K=256; wave wv owns cols [wv*64, wv*64+64)
  f32x4 pr[4][4];
  #pragma unroll
  for (int tn = 0; tn < 4; ++tn) {
    float bv = proj_b[(wv << 6) + (tn << 4) + lr];
    f32x4 z = {bv, bv, bv, bv};
    #pragma unroll
    for (int tm = 0; tm < 4; ++tm) pr[tm][tn] = z;
  }
  #pragma unroll 2
  for (int kk = 0; kk < 8; ++kk) {
    const int c0 = kk << 5;
    bf16x8 a[4], bw[4];
    #pragma unroll
    for (int tm = 0; tm < 4; ++tm)
      a[tm] = *(const bf16x8*)&T[idx256((tm << 4) + lr, c0 + (lg << 3))];
    #pragma unroll
    for (int tn = 0; tn < 4; ++tn)
      bw[tn] = *(const bf16x8*)&projw[(((wv << 6) + (tn << 4) + lr) << 8) + c0 + (lg << 3)];
    #pragma unroll
    for (int tm = 0; tm < 4; ++tm)
      #pragma unroll
      for (int tn = 0; tn < 4; ++tn)
        pr[tm][tn] = MFMA16(a[tm], bw[tn], pr[tm][tn]);
  }
  __syncthreads();  // all T reads complete

  // phase 3: write pr into T, rotated layout keyed by row&252 (matches reader)
  #pragma unroll
  for (int tm = 0; tm < 4; ++tm)
    #pragma unroll
    for (int tn = 0; tn < 4; ++tn)
      #pragma unroll
      for (int rj = 0; rj < 4; ++rj) {
        int r = (tm << 4) + (lg << 2) + rj;
        int col = (wv << 6) + (tn << 4) + lr;
        T[(r << 8) + ((col + (r & 252)) & 255)] = f2bf(pr[tm][tn][rj]);
      }
  __syncthreads();

  // phase 4: residual add + channel-major store (coalesced along W)
  int wq = threadIdx.x & 15, c_lo = threadIdx.x >> 4;
  int w0 = wq << 2;
  for (int c_hi = 0; c_hi < 16; ++c_hi) {
    int c = (c_hi << 4) + c_lo;
    size_t gbase = (((size_t)(b * 256 + c)) << 16) + (sd << 12) + (sh << 6) + w0;
    float4 xv = *(const float4*)(x + gbase);
    int cp = (c + w0) & 255;
    float4 o;
    o.x = xv.x + bf2f(T[((w0 + 0) << 8) + cp]);
    o.y = xv.y + bf2f(T[((w0 + 1) << 8) + cp]);
    o.z = xv.z + bf2f(T[((w0 + 2) << 8) + cp]);
    o.w = xv.w + bf2f(T[((w0 + 3) << 8) + cp]);
    *(float4*)(out + gbase) = o;
  }
}

extern "C" void kernel_launch(void* const* d_in, const int* in_sizes, int n_in,
                              void* d_out, int out_size, void* d_ws, size_t ws_size,
                              hipStream_t stream) {
  const float* x      = (const float*)d_in[0];
  const float* norm_w = (const float*)d_in[1];
  const float* norm_b = (const float*)d_in[2];
  const float* qkv_w  = (const float*)d_in[3];
  const float* qkv_b  = (const float*)d_in[4];
  const float* rpb    = (const float*)d_in[5];
  const float* proj_w = (const float*)d_in[6];
  const float* proj_b = (const float*)d_in[7];
  float* out = (float*)d_out;

  char* ws = (char*)d_ws;
  float* stats  = (float*)ws;                      // 512 B
  float* part   = (float*)(ws + 512);              // 8192 B
  u16* qkvw     = (u16*)(ws + 8704);               // 393216 B
  u16* projw    = (u16*)(ws + 401920);             // 131072 B
  float* biast2 = (float*)(ws + 532992);           // 131072 B
  u16* stage    = (u16*)(ws + 664064);             // 64 MB (XN, then O in place)

  hipLaunchKernelGGL(k_prep, dim3(768), dim3(256), 0, stream, qkv_w, proj_w, rpb,
                     qkvw, projw, biast2);
  hipLaunchKernelGGL(k_stats1, dim3(1024), dim3(256), 0, stream, x, part);
  hipLaunchKernelGGL(k_stats2, dim3(1), dim3(64), 0, stream, part, stats);
  hipLaunchKernelGGL(k_win, dim3(2048), dim3(256), 0, stream, x, norm_w, norm_b,
                     stats, stage);
  hipLaunchKernelGGL(k_attn, dim3(4096), dim3(256), 0, stream, qkv_b, qkvw,
                     biast2, stage);
  hipLaunchKernelGGL(k_pout, dim3(2048), dim3(256), 0, stream, x, stage,
                     proj_b, projw, out);
}

// Round 19
// 256.488 us; speedup vs baseline: 1.0575x; 1.0575x over previous
//
#include <hip/hip_runtime.h>

typedef unsigned short u16;
typedef __attribute__((ext_vector_type(4))) unsigned short u16x4;
typedef __attribute__((ext_vector_type(2))) unsigned int u32x2;
typedef __attribute__((ext_vector_type(4))) unsigned int u32x4;
typedef __attribute__((ext_vector_type(4))) short s16x4;
typedef __attribute__((ext_vector_type(8))) short bf16x8;
typedef __attribute__((ext_vector_type(4))) float f32x4;

#define MFMA16(a, b, c) __builtin_amdgcn_mfma_f32_16x16x32_bf16((a), (b), (c), 0, 0, 0)
// K=16 MFMA: A/B frag k-layout = lg*4+{0..3} == C-layout acc row grouping ->
// C-layout accumulators feed it with ZERO cross-lane movement. (r11 proven)
#define MFMAK16(a, b, c) \
  __builtin_amdgcn_mfma_f32_16x16x16bf16_1k( \
      __builtin_bit_cast(s16x4, (a)), __builtin_bit_cast(s16x4, (b)), (c), 0, 0, 0)

__device__ __forceinline__ u16 f2bf(float f) {
  unsigned u = __builtin_bit_cast(unsigned, f);
  u += 0x7FFFu + ((u >> 16) & 1u);  // round-to-nearest-even
  return (u16)(u >> 16);
}
__device__ __forceinline__ float bf2f(u16 v) {
  return __builtin_bit_cast(float, (unsigned)v << 16);
}
__device__ __forceinline__ unsigned cvtpk(float lo, float hi) {
  unsigned r;
  asm("v_cvt_pk_bf16_f32 %0, %1, %2" : "=v"(r) : "v"(lo), "v"(hi));
  return r;
}

// XOR-swizzled [64][256] bf16: 16-B block (r*32 + c>>3)^(r&7)
__device__ __forceinline__ int idx256(int r, int c) {
  int blk = ((r << 5) + (c >> 3)) ^ (r & 7);
  return (blk << 3) + (c & 7);
}

// ---------------- stats pass 1 ----------------
__global__ __launch_bounds__(256) void k_stats1(const float* __restrict__ x,
                                                float* __restrict__ part) {
  int bid = blockIdx.x;
  int s = bid & 15, bg = bid >> 4;
  const float4* p = (const float4*)(x + ((size_t)bg << 19) + ((size_t)s << 15));
  float sm = 0.f, ss = 0.f;
  for (int i = threadIdx.x; i < 8192; i += 256) {
    float4 v = p[i];
    sm += v.x + v.y + v.z + v.w;
    ss += v.x * v.x + v.y * v.y + v.z * v.z + v.w * v.w;
  }
  #pragma unroll
  for (int off = 1; off < 64; off <<= 1) {
    sm += __shfl_xor(sm, off);
    ss += __shfl_xor(ss, off);
  }
  __shared__ float ls[4], lss[4];
  int wv = threadIdx.x >> 6;
  if ((threadIdx.x & 63) == 0) { ls[wv] = sm; lss[wv] = ss; }
  __syncthreads();
  if (threadIdx.x == 0) {
    part[bid * 2] = ls[0] + ls[1] + ls[2] + ls[3];
    part[bid * 2 + 1] = lss[0] + lss[1] + lss[2] + lss[3];
  }
}

// ---------------- stats pass 2 ----------------
__global__ __launch_bounds__(64) void k_stats2(const float* __restrict__ part,
                                               float* __restrict__ stats) {
  int t = threadIdx.x;
  float S = 0.f, SS = 0.f;
  #pragma unroll
  for (int s = 0; s < 16; ++s) {
    S += part[(t * 16 + s) * 2];
    SS += part[(t * 16 + s) * 2 + 1];
  }
  const float inv = 1.f / 524288.f;
  float mean = S * inv;
  float var = SS * inv - mean * mean;
  stats[t * 2] = mean;
  stats[t * 2 + 1] = rsqrtf(var + 1e-5f);
}

// ------- weights bf16 + lane-permuted bias table [h][tile16][lane64][rj4] * log2e -------
__global__ __launch_bounds__(256) void k_prep(const float* __restrict__ qkv_w,
                                              const float* __restrict__ proj_w,
                                              const float* __restrict__ rpb,
                                              u16* __restrict__ qkvw,
                                              u16* __restrict__ projw,
                                              float* __restrict__ biast2) {
  int i = blockIdx.x * 256 + threadIdx.x;
  if (i < 196608) qkvw[i] = f2bf(qkv_w[i]);
  if (i < 65536) projw[i] = f2bf(proj_w[i]);
  if (i < 32768) {
    int h = i >> 12;
    int rem = i & 4095;
    int tile = rem >> 8, lane = (rem >> 2) & 63, rj = rem & 3;
    int tms = tile >> 2, tq = tile & 3;
    int lg = lane >> 4, lr = lane & 15;
    int key = (tms << 4) + (lg << 2) + rj;
    int q = (tq << 4) + lr;
    int qd = q >> 4, qh = (q >> 2) & 3, qw = q & 3;
    int kd = key >> 4, kh = (key >> 2) & 3, kw = key & 3;
    int r = (qd - kd + 3) * 49 + (qh - kh + 3) * 7 + (qw - kw + 3);
    biast2[i] = rpb[r * 8 + h] * 1.4426950408889634f;
  }
}

// ---------------- norm + window partition + transpose -> stage ----------------
__global__ __launch_bounds__(256) void k_win(const float* __restrict__ x,
                                             const float* __restrict__ norm_w,
                                             const float* __restrict__ norm_b,
                                             const float* __restrict__ stats,
                                             u16* __restrict__ stage) {
  __shared__ __attribute__((aligned(16))) u16 T[16384];
  int bid = blockIdx.x;
  int b = bid >> 10, sd = (bid >> 6) & 15, sh = bid & 63;
  int wq = threadIdx.x & 15, c_lo = threadIdx.x >> 4;
  int w0 = wq << 2;

  for (int c_hi = 0; c_hi < 16; ++c_hi) {
    int c = (c_hi << 4) + c_lo;
    int g = c >> 3;
    float mean = stats[((b << 5) + g) * 2];
    float rstd = stats[((b << 5) + g) * 2 + 1];
    float gw = norm_w[c] * rstd;
    float gb = norm_b[c] - mean * gw;
    float4 v = *(const float4*)(x + (((size_t)(b * 256 + c)) << 16) + (sd << 12) +
                                (sh << 6) + w0);
    int cp = (c + w0) & 255;
    T[((w0 + 0) << 8) + cp] = f2bf(fmaf(v.x, gw, gb));
    T[((w0 + 1) << 8) + cp] = f2bf(fmaf(v.y, gw, gb));
    T[((w0 + 2) << 8) + cp] = f2bf(fmaf(v.z, gw, gb));
    T[((w0 + 3) << 8) + cp] = f2bf(fmaf(v.w, gw, gb));
  }
  __syncthreads();

  int wv = threadIdx.x >> 6, l = threadIdx.x & 63;
  int ud = (sd + 14) & 15, wd = ud >> 2, td = ud & 3;
  int uh = (sh + 62) & 63, wh = uh >> 2, th = uh & 3;
  int winbase = (b << 10) + (wd << 8) + (wh << 4);
  int tokbase = (td << 4) + (th << 2);
  for (int it = 0; it < 16; ++it) {
    int sw = (it << 2) + wv;
    int uw = (sw + 62) & 63, ww = uw >> 2, tw = uw & 3;
    int row = ((winbase + ww) << 6) + tokbase + tw;
    u16x4 val = *(const u16x4*)&T[(sw << 8) + (((l << 2) + (sw & 252)) & 255)];
    *(u16x4*)&stage[((size_t)row << 8) + (l << 2)] = val;
  }
}

// ------- attention: 512 thr / 8 waves, 1 head/wave, two-pass QKV (register diet),
//         direct O stores, both halves unrolled (r17 best config) -------
__global__ __launch_bounds__(512) void k_attn(
    const float* __restrict__ qkv_b, const u16* __restrict__ qkvw,
    const float* __restrict__ biast2, u16* __restrict__ stage) {
  __shared__ __attribute__((aligned(16))) u16 sXN[16384];  // 32 KB [64][256] swz

  const int tid = threadIdx.x;
  const int win = blockIdx.x;
  const int lane = tid & 63;
  const int wv = tid >> 6;  // == head
  const int lr = lane & 15;
  const int lg = lane >> 4;
  u16* wbase = stage + ((size_t)win << 14);

  // phase 1: coalesced pre-swizzled load of the window into sXN
  #pragma unroll
  for (int it = 0; it < 4; ++it) {
    int r = (it << 4) + (wv << 1) + (lane >> 5);
    int p = lane & 31;
    u32x4 v = *(const u32x4*)(wbase + (r << 8) + ((p ^ (r & 7)) << 3));
    *(u32x4*)&sXN[(r << 8) + (p << 3)] = v;
  }
  __syncthreads();  // the only barrier

  // 1/sqrt(32) * log2(e): softmax runs in exp2 domain
  const float SCALE = 0.17677669529663687f * 1.4426950408889634f;
  const int h = wv;
  const int woQ = (h << 5);
  const int woK = 256 + (h << 5);
  const int woV = 512 + (h << 5);

  u32x2 qB[2][4], kA[2][4], vB[4][2];

  // ---- Pass A: Q,K operand-swapped (acc [d][tok]); peak live acc = 64 f32 ----
  {
    f32x4 aQ[2][4], aK[2][4];
    float4 q0 = *(const float4*)&qkv_b[woQ + (lg << 2)];
    float4 q1 = *(const float4*)&qkv_b[woQ + 16 + (lg << 2)];
    float4 k0 = *(const float4*)&qkv_b[woK + (lg << 2)];
    float4 k1 = *(const float4*)&qkv_b[woK + 16 + (lg << 2)];
    #pragma unroll
    for (int xt = 0; xt < 4; ++xt) {
      aQ[0][xt][0] = q0.x; aQ[0][xt][1] = q0.y; aQ[0][xt][2] = q0.z; aQ[0][xt][3] = q0.w;
      aQ[1][xt][0] = q1.x; aQ[1][xt][1] = q1.y; aQ[1][xt][2] = q1.z; aQ[1][xt][3] = q1.w;
      aK[0][xt][0] = k0.x; aK[0][xt][1] = k0.y; aK[0][xt][2] = k0.z; aK[0][xt][3] = k0.w;
      aK[1][xt][0] = k1.x; aK[1][xt][1] = k1.y; aK[1][xt][2] = k1.z; aK[1][xt][3] = k1.w;
    }
    #pragma unroll 2
    for (int kk = 0; kk < 8; ++kk) {
      const int c0 = kk << 5;
      bf16x8 xb[4], wq_[2], wk_[2];
      #pragma unroll
      for (int t = 0; t < 4; ++t)
        xb[t] = *(const bf16x8*)&sXN[idx256((t << 4) + lr, c0 + (lg << 3))];
      #pragma unroll
      for (int t = 0; t < 2; ++t) {
        wq_[t] = *(const bf16x8*)&qkvw[((woQ + (t << 4) + lr) << 8) + c0 + (lg << 3)];
        wk_[t] = *(const bf16x8*)&qkvw[((woK + (t << 4) + lr) << 8) + c0 + (lg << 3)];
      }
      #pragma unroll
      for (int wt = 0; wt < 2; ++wt)
        #pragma unroll
        for (int xt = 0; xt < 4; ++xt) {
          aQ[wt][xt] = MFMA16(wq_[wt], xb[xt], aQ[wt][xt]);
          aK[wt][xt] = MFMA16(wk_[wt], xb[xt], aK[wt][xt]);
        }
    }
    #pragma unroll
    for (int wt = 0; wt < 2; ++wt)
      #pragma unroll
      for (int xt = 0; xt < 4; ++xt) {
        u32x2 tq = {cvtpk(aQ[wt][xt][0] * SCALE, aQ[wt][xt][1] * SCALE),
                    cvtpk(aQ[wt][xt][2] * SCALE, aQ[wt][xt][3] * SCALE)};
        qB[wt][xt] = tq;
        u32x2 tk = {cvtpk(aK[wt][xt][0], aK[wt][xt][1]),
                    cvtpk(aK[wt][xt][2], aK[wt][xt][3])};
        kA[wt][xt] = tk;
      }
  }

  // ---- Pass B: V normal (acc [tok][d]); peak live acc = 32 f32 ----
  {
    f32x4 aV[4][2];
    float v0 = qkv_b[woV + lr];
    float v1 = qkv_b[woV + 16 + lr];
    #pragma unroll
    for (int tm = 0; tm < 4; ++tm) {
      f32x4 z0 = {v0, v0, v0, v0};
      f32x4 z1 = {v1, v1, v1, v1};
      aV[tm][0] = z0;
      aV[tm][1] = z1;
    }
    #pragma unroll 2
    for (int kk = 0; kk < 8; ++kk) {
      const int c0 = kk << 5;
      bf16x8 xb[4], wv_[2];
      #pragma unroll
      for (int t = 0; t < 4; ++t)
        xb[t] = *(const bf16x8*)&sXN[idx256((t << 4) + lr, c0 + (lg << 3))];
      #pragma unroll
      for (int t = 0; t < 2; ++t)
        wv_[t] = *(const bf16x8*)&qkvw[((woV + (t << 4) + lr) << 8) + c0 + (lg << 3)];
      #pragma unroll
      for (int tm = 0; tm < 4; ++tm)
        #pragma unroll
        for (int td = 0; td < 2; ++td)
          aV[tm][td] = MFMA16(xb[tm], wv_[td], aV[tm][td]);
    }
    #pragma unroll
    for (int tm = 0; tm < 4; ++tm)
      #pragma unroll
      for (int td = 0; td < 2; ++td) {
        u32x2 tv = {cvtpk(aV[tm][td][0], aV[tm][td][1]),
                    cvtpk(aV[tm][td][2], aV[tm][td][3])};
        vB[tm][td] = tv;
      }
  }

  // ---- S^T + softmax + PV, both halves unrolled (independent chains) ----
  #pragma unroll
  for (int half = 0; half < 2; ++half) {
    f32x4 s2[4][2];
    #pragma unroll
    for (int tms = 0; tms < 4; ++tms)
      #pragma unroll
      for (int tn2 = 0; tn2 < 2; ++tn2)
        s2[tms][tn2] = *(const f32x4*)&biast2[
            (((h << 4) + (tms << 2) + (half << 1) + tn2) << 8) + (lane << 2)];
    __builtin_amdgcn_s_setprio(1);
    #pragma unroll
    for (int tms = 0; tms < 4; ++tms)
      #pragma unroll
      for (int tn2 = 0; tn2 < 2; ++tn2) {
        s2[tms][tn2] = MFMAK16(kA[0][tms], qB[0][(half << 1) + tn2], s2[tms][tn2]);
        s2[tms][tn2] = MFMAK16(kA[1][tms], qB[1][(half << 1) + tn2], s2[tms][tn2]);
      }
    __builtin_amdgcn_s_setprio(0);

    // softmax over keys, exp2 domain, no max-subtract (|S| bounded; r15 proven)
    #pragma unroll
    for (int tn2 = 0; tn2 < 2; ++tn2) {
      float sum = 0.f;
      #pragma unroll
      for (int tms = 0; tms < 4; ++tms)
        #pragma unroll
        for (int rj = 0; rj < 4; ++rj) {
          float e = exp2f(s2[tms][tn2][rj]);
          s2[tms][tn2][rj] = e;
          sum += e;
        }
      sum += __shfl_xor(sum, 16);
      sum += __shfl_xor(sum, 32);
      float inv = 1.f / sum;
      #pragma unroll
      for (int tms = 0; tms < 4; ++tms)
        #pragma unroll
        for (int rj = 0; rj < 4; ++rj) s2[tms][tn2][rj] *= inv;
    }

    // P as K16 A-frag directly from s2 (lane lr = q, k = key rows): cvt_pk only
    u32x2 pf[4][2];
    #pragma unroll
    for (int tms = 0; tms < 4; ++tms)
      #pragma unroll
      for (int tn2 = 0; tn2 < 2; ++tn2) {
        u32x2 t = {cvtpk(s2[tms][tn2][0], s2[tms][tn2][1]),
                   cvtpk(s2[tms][tn2][2], s2[tms][tn2][3])};
        pf[tms][tn2] = t;
      }

    // O[q][d] = P·V : o[tn2(q-tile)][dt(d-tile)], accumulate over 4 key-tiles
    f32x4 o[2][2];
    {
      f32x4 z = {0.f, 0.f, 0.f, 0.f};
      #pragma unroll
      for (int tn2 = 0; tn2 < 2; ++tn2)
        #pragma unroll
        for (int dt = 0; dt < 2; ++dt) o[tn2][dt] = z;
    }
    __builtin_amdgcn_s_setprio(1);
    #pragma unroll
    for (int tms = 0; tms < 4; ++tms)
      #pragma unroll
      for (int tn2 = 0; tn2 < 2; ++tn2)
        #pragma unroll
        for (int dt = 0; dt < 2; ++dt)
          o[tn2][dt] = MFMAK16(pf[tms][tn2], vB[tms][dt], o[tn2][dt]);
    __builtin_amdgcn_s_setprio(0);

    // direct global O stores (in-place over stage; sXN copy already made).
    // token q = (half<<5)+(tn2<<4)+(lg<<2)+rj, ch = (h<<5)+(dt<<4)+lr
    #pragma unroll
    for (int tn2 = 0; tn2 < 2; ++tn2)
      #pragma unroll
      for (int dt = 0; dt < 2; ++dt)
        #pragma unroll
        for (int rj = 0; rj < 4; ++rj) {
          int q = (half << 5) + (tn2 << 4) + (lg << 2) + rj;
          wbase[(q << 8) + (h << 5) + (dt << 4) + lr] = f2bf(o[tn2][dt][rj]);
        }
  }
}

// ---------------- proj GEMM + window reverse + residual (fused) ----------------
__global__ __launch_bounds__(256, 4) void k_pout(
    const float* __restrict__ x, const u16* __restrict__ stage,
    const float* __restrict__ proj_b, const u16* __restrict__ projw,
    float* __restrict__ out) {
  __shared__ __attribute__((aligned(16))) u16 T[16384];  // 32 KB, reused per phase
  int bid = blockIdx.x;
  int b = bid >> 10, sd = (bid >> 6) & 15, sh = bid & 63;
  int wv = threadIdx.x >> 6, l = threadIdx.x & 63;
  int lr = l & 15, lg = l >> 4;
  int ud = (sd + 14) & 15, wd = ud >> 2, td = ud & 3;
  int uh = (sh + 62) & 63, wh = uh >> 2, th = uh & 3;
  int winbase = (b << 10) + (wd << 8) + (wh << 4);
  int tokbase = (td << 4) + (th << 2);

  // phase 1: gather O rows (coalesced 512-B) -> T in idx256-swizzled layout
  #pragma unroll
  for (int it = 0; it < 16; ++it) {
    int sw = (it << 2) + wv;
    int uw = (sw + 62) & 63, ww = uw >> 2, tw = uw & 3;
    int row = ((winbase + ww) << 6) + tokbase + tw;
    u16x4 val = *(const u16x4*)&stage[((size_t)row << 8) + (l << 2)];
    int blk = ((sw << 5) + (l >> 1)) ^ (sw & 7);
    *(u16x4*)&T[(blk << 3) + ((l & 1) << 2)] = val;
  }
  __syncthreads();

  // phase 2: proj GEMM 64x256, K=256; wave wv owns cols [wv*64, wv*64+64)
  f32x4 pr[4][4];
  #pragma unroll
  for (int tn = 0; tn < 4; ++tn) {
    float bv = proj_b[(wv << 6) + (tn << 4) + lr];
    f32x4 z = {bv, bv, bv, bv};
    #pragma unroll
    for (int tm = 0; tm < 4; ++tm) pr[tm][tn] = z;
  }
  #pragma unroll 2
  for (int kk = 0; kk < 8; ++kk) {
    const int c0 = kk << 5;
    bf16x8 a[4], bw[4];
    #pragma unroll
    for (int tm = 0; tm < 4; ++tm)
      a[tm] = *(const bf16x8*)&T[idx256((tm << 4) + lr, c0 + (lg << 3))];
    #pragma unroll
    for (int tn = 0; tn < 4; ++tn)
      bw[tn] = *(const bf16x8*)&projw[(((wv << 6) + (tn << 4) + lr) << 8) + c0 + (lg << 3)];
    #pragma unroll
    for (int tm = 0; tm < 4; ++tm)
      #pragma unroll
      for (int tn = 0; tn < 4; ++tn)
        pr[tm][tn] = MFMA16(a[tm], bw[tn], pr[tm][tn]);
  }
  __syncthreads();  // all T reads complete

  // phase 3: write pr into T, rotated layout keyed by row&252 (matches reader)
  #pragma unroll
  for (int tm = 0; tm < 4; ++tm)
    #pragma unroll
    for (int tn = 0; tn < 4; ++tn)
      #pragma unroll
      for (int rj = 0; rj < 4; ++rj) {
        int r = (tm << 4) + (lg << 2) + rj;
        int col = (wv << 6) + (tn << 4) + lr;
        T[(r << 8) + ((col + (r & 252)) & 255)] = f2bf(pr[tm][tn][rj]);
      }
  __syncthreads();

  // phase 4: residual add + channel-major store (coalesced along W)
  int wq = threadIdx.x & 15, c_lo = threadIdx.x >> 4;
  int w0 = wq << 2;
  for (int c_hi = 0; c_hi < 16; ++c_hi) {
    int c = (c_hi << 4) + c_lo;
    size_t gbase = (((size_t)(b * 256 + c)) << 16) + (sd << 12) + (sh << 6) + w0;
    float4 xv = *(const float4*)(x + gbase);
    int cp = (c + w0) & 255;
    float4 o;
    o.x = xv.x + bf2f(T[((w0 + 0) << 8) + cp]);
    o.y = xv.y + bf2f(T[((w0 + 1) << 8) + cp]);
    o.z = xv.z + bf2f(T[((w0 + 2) << 8) + cp]);
    o.w = xv.w + bf2f(T[((w0 + 3) << 8) + cp]);
    *(float4*)(out + gbase) = o;
  }
}

extern "C" void kernel_launch(void* const* d_in, const int* in_sizes, int n_in,
                              void* d_out, int out_size, void* d_ws, size_t ws_size,
                              hipStream_t stream) {
  const float* x      = (const float*)d_in[0];
  const float* norm_w = (const float*)d_in[1];
  const float* norm_b = (const float*)d_in[2];
  const float* qkv_w  = (const float*)d_in[3];
  const float* qkv_b  = (const float*)d_in[4];
  const float* rpb    = (const float*)d_in[5];
  const float* proj_w = (const float*)d_in[6];
  const float* proj_b = (const float*)d_in[7];
  float* out = (float*)d_out;

  char* ws = (char*)d_ws;
  float* stats  = (float*)ws;                      // 512 B
  float* part   = (float*)(ws + 512);              // 8192 B
  u16* qkvw     = (u16*)(ws + 8704);               // 393216 B
  u16* projw    = (u16*)(ws + 401920);             // 131072 B
  float* biast2 = (float*)(ws + 532992);           // 131072 B
  u16* stage    = (u16*)(ws + 664064);             // 64 MB (XN, then O in place)

  hipLaunchKernelGGL(k_prep, dim3(768), dim3(256), 0, stream, qkv_w, proj_w, rpb,
                     qkvw, projw, biast2);
  hipLaunchKernelGGL(k_stats1, dim3(1024), dim3(256), 0, stream, x, part);
  hipLaunchKernelGGL(k_stats2, dim3(1), dim3(64), 0, stream, part, stats);
  hipLaunchKernelGGL(k_win, dim3(2048), dim3(256), 0, stream, x, norm_w, norm_b,
                     stats, stage);
  hipLaunchKernelGGL(k_attn, dim3(2048), dim3(512), 0, stream, qkv_b, qkvw,
                     biast2, stage);
  hipLaunchKernelGGL(k_pout, dim3(2048), dim3(256), 0, stream, x, stage,
                     proj_b, projw, out);
}